// Round 1
// baseline (1280.346 us; speedup 1.0000x reference)
//
#include <hip/hip_runtime.h>
#include <math.h>

// Problem constants
#define NB 16     // batch
#define SQ 40     // seq len
#define HIDN 256  // hidden = E = R
#define CC 1024   // C
#define NROW 262144 // R*C

__device__ __forceinline__ float sigf(float x){ return 1.0f/(1.0f+__expf(-x)); }
__device__ __forceinline__ float bflo(unsigned u){ return __uint_as_float(u<<16); }
__device__ __forceinline__ float bfhi(unsigned u){ return __uint_as_float(u & 0xffff0000u); }
// monotone float->uint encoding for atomicMax over floats (any sign)
__device__ __forceinline__ unsigned encf(float x){
  unsigned u = __float_as_uint(x);
  return (u & 0x80000000u) ? ~u : (u | 0x80000000u);
}

__device__ __forceinline__ float dot8(uint4 u, float4 a, float4 b){
  return bflo(u.x)*a.x + bfhi(u.x)*a.y + bflo(u.y)*a.z + bfhi(u.y)*a.w
       + bflo(u.z)*b.x + bfhi(u.z)*b.y + bflo(u.w)*b.z + bfhi(u.w)*b.w;
}

// ---------------- K0: x-gates precompute: XG[t*16+b][row] = emb[idx[b][t]] . w_ih[row] + b_ih + b_hh
__global__ __launch_bounds__(256) void k_xgates(
    const int* __restrict__ idx, const float* __restrict__ emb,
    const float* __restrict__ w_ih, const float* __restrict__ b_ih,
    const float* __restrict__ b_hh, float* __restrict__ XG)
{
  __shared__ float xs[8*256];
  int t = threadIdx.x;
  int tb0 = blockIdx.x * 8;
  #pragma unroll
  for (int i = 0; i < 8; ++i) {
    int flat = t + i*256;
    int p = flat >> 8, k = flat & 255;
    int tb = tb0 + p;
    int ts = tb >> 4, b = tb & 15;
    int row = idx[b*SQ + ts];
    xs[p*256 + k] = emb[row*256 + k];
  }
  __syncthreads();
  int rows[4];
  float acc[4][8];
  #pragma unroll
  for (int r = 0; r < 4; ++r) {
    rows[r] = t + r*256;
    float bias = b_ih[rows[r]] + b_hh[rows[r]];
    #pragma unroll
    for (int p = 0; p < 8; ++p) acc[r][p] = bias;
  }
  for (int k16 = 0; k16 < 16; ++k16) {
    float4 w[4][4];
    #pragma unroll
    for (int r = 0; r < 4; ++r)
      #pragma unroll
      for (int q = 0; q < 4; ++q)
        w[r][q] = *(const float4*)&w_ih[rows[r]*256 + k16*16 + q*4];
    #pragma unroll
    for (int p = 0; p < 8; ++p) {
      #pragma unroll
      for (int q = 0; q < 4; ++q) {
        float4 x = *(const float4*)&xs[p*256 + k16*16 + q*4];
        #pragma unroll
        for (int r = 0; r < 4; ++r)
          acc[r][p] += w[r][q].x*x.x + w[r][q].y*x.y + w[r][q].z*x.z + w[r][q].w*x.w;
      }
    }
  }
  #pragma unroll
  for (int p = 0; p < 8; ++p)
    #pragma unroll
    for (int r = 0; r < 4; ++r)
      XG[(tb0 + p)*1024 + rows[r]] = acc[r][p];
}

// ---------------- Kconv: pack w_hh fp32 -> bf16 pairs (RNE)
__global__ __launch_bounds__(256) void k_conv_whh(const float* __restrict__ w, unsigned* __restrict__ o)
{
  int i = blockIdx.x*256 + threadIdx.x; // 131072 total
  float2 v = ((const float2*)w)[i];
  unsigned a = __float_as_uint(v.x), b = __float_as_uint(v.y);
  a = (a + 0x7fffu + ((a>>16)&1u)) >> 16;
  b = (b + 0x7fffu + ((b>>16)&1u)) >> 16;
  o[i] = a | (b<<16);
}

// ---------------- K1: recurrent LSTM (one block per batch) + e2d tanh head
__global__ __launch_bounds__(256) void k_lstm(
    const float* __restrict__ XG, const unsigned* __restrict__ whh,
    const int* __restrict__ lens, const float* __restrict__ e2d_w,
    const float* __restrict__ e2d_b, float* __restrict__ instr)
{
  __shared__ float hs[256];
  int j = threadIdx.x, b = blockIdx.x;
  int len_b = lens[b];
  float c = 0.0f, hv = 0.0f;
  hs[j] = 0.0f;
  __syncthreads();
  const uint4* wr0 = (const uint4*)&whh[(j      )*128];
  const uint4* wr1 = (const uint4*)&whh[(j+256)*128];
  const uint4* wr2 = (const uint4*)&whh[(j+512)*128];
  const uint4* wr3 = (const uint4*)&whh[(j+768)*128];
  for (int ts = 0; ts < SQ; ++ts) {
    const float* xg = &XG[(ts*NB + b)*1024];
    float a0 = xg[j], a1 = xg[j+256], a2 = xg[j+512], a3 = xg[j+768];
    for (int k32 = 0; k32 < 8; ++k32) {
      uint4 u0[4], u1[4], u2[4], u3[4];
      #pragma unroll
      for (int q = 0; q < 4; ++q) {
        u0[q] = wr0[k32*4+q]; u1[q] = wr1[k32*4+q];
        u2[q] = wr2[k32*4+q]; u3[q] = wr3[k32*4+q];
      }
      #pragma unroll
      for (int q = 0; q < 4; ++q) {
        float4 hA = *(const float4*)&hs[k32*32 + q*8];
        float4 hB = *(const float4*)&hs[k32*32 + q*8 + 4];
        a0 += dot8(u0[q], hA, hB);
        a1 += dot8(u1[q], hA, hB);
        a2 += dot8(u2[q], hA, hB);
        a3 += dot8(u3[q], hA, hB);
      }
    }
    float ig = sigf(a0), fg = sigf(a1), gg = tanhf(a2), og = sigf(a3);
    float cn = fg*c + ig*gg;
    float hn = og*tanhf(cn);
    if (ts < len_b) { c = cn; hv = hn; }
    __syncthreads();   // all reads of old h done
    hs[j] = hv;
    __syncthreads();
  }
  // e2d head: instr[b][j] = tanh(h . e2d_w[j] + e2d_b[j])
  float acc = e2d_b[j];
  const float* wr = &e2d_w[j*256];
  #pragma unroll 8
  for (int k4 = 0; k4 < 64; ++k4) {
    float4 h4 = *(const float4*)&hs[k4*4];
    float4 w4 = *(const float4*)&wr[k4*4];
    acc += w4.x*h4.x + w4.y*h4.y + w4.z*h4.z + w4.w*h4.w;
  }
  instr[b*256 + j] = tanhf(acc);
}

// ---------------- K2: lin1: f1[b][rc] = leaky(instr[b] . lin1_w[rc] + lin1_b[rc]); 2 rows/thread, 512 blocks
__global__ __launch_bounds__(256) void k_lin1(
    const float* __restrict__ instr, const float* __restrict__ w,
    const float* __restrict__ bias, float* __restrict__ f1)
{
  __shared__ float is[4096];
  int t = threadIdx.x;
  #pragma unroll
  for (int i = 0; i < 16; ++i) is[t + i*256] = instr[t + i*256];
  __syncthreads();
  int r0 = blockIdx.x*512 + t;
  int r1 = r0 + 256;
  const float* w0 = &w[(size_t)r0*256];
  const float* w1 = &w[(size_t)r1*256];
  float acc0[16], acc1[16];
  float bz0 = bias[r0], bz1 = bias[r1];
  #pragma unroll
  for (int i = 0; i < 16; ++i){ acc0[i]=bz0; acc1[i]=bz1; }
  for (int k16 = 0; k16 < 16; ++k16) {
    float4 a[4], bb[4];
    #pragma unroll
    for (int q = 0; q < 4; ++q){
      a[q]  = *(const float4*)&w0[k16*16 + q*4];
      bb[q] = *(const float4*)&w1[k16*16 + q*4];
    }
    #pragma unroll
    for (int bi = 0; bi < 16; ++bi) {
      #pragma unroll
      for (int q = 0; q < 4; ++q) {
        float4 x = *(const float4*)&is[bi*256 + k16*16 + q*4]; // uniform addr -> LDS broadcast
        acc0[bi] += a[q].x*x.x + a[q].y*x.y + a[q].z*x.z + a[q].w*x.w;
        acc1[bi] += bb[q].x*x.x + bb[q].y*x.y + bb[q].z*x.z + bb[q].w*x.w;
      }
    }
  }
  #pragma unroll
  for (int bi = 0; bi < 16; ++bi) {
    float v0 = acc0[bi]; v0 = v0 > 0.0f ? v0 : 0.01f*v0;
    float v1 = acc1[bi]; v1 = v1 > 0.0f ? v1 : 0.01f*v1;
    f1[bi*NROW + r0] = v0;
    f1[bi*NROW + r1] = v1;
  }
}

// ---------------- K3: per-batch gemm f1[b](256x1024) @ feat[b](1024x1024), fused relu->BN->max_r via atomicMax
__global__ __launch_bounds__(256) void k_einsum_max(
    const float* __restrict__ f1, const float* __restrict__ feat,
    const float* __restrict__ gamma, const float* __restrict__ beta,
    const float* __restrict__ mean, const float* __restrict__ var,
    unsigned* __restrict__ M)
{
  __shared__ float aT[16*128];      // [k][r]
  __shared__ float bT[16*128];      // [k][p]
  __shared__ unsigned Lred[128];
  int tid = threadIdx.x;
  int b   = blockIdx.x >> 4;
  int rem = blockIdx.x & 15;
  int R0  = (rem >> 3) * 128;
  int P0  = (rem & 7) * 128;
  int tx = tid & 15, ty = tid >> 4;
  if (tid < 128) Lred[tid] = 0u;
  float acc[8][8];
  #pragma unroll
  for (int i=0;i<8;++i)
    #pragma unroll
    for (int j2=0;j2<8;++j2) acc[i][j2]=0.0f;
  int ra = tid >> 1, ha = (tid & 1) * 8;   // A staging: row, k-offset
  int kb = tid >> 4, sb = (tid & 15) * 8;  // B staging: k, p-offset
  const float* Abase = &f1[(b*256 + R0 + ra)*1024 + ha];
  const float* Bbase = &feat[((b*1024) + kb)*1024 + P0 + sb];
  for (int kk = 0; kk < 64; ++kk) {
    int k0 = kk*16;
    __syncthreads();
    float4 av0 = *(const float4*)&Abase[k0];
    float4 av1 = *(const float4*)&Abase[k0+4];
    float4 bv0 = *(const float4*)&Bbase[(size_t)k0*1024];
    float4 bv1 = *(const float4*)&Bbase[(size_t)k0*1024 + 4];
    aT[(ha+0)*128 + ra] = av0.x;  aT[(ha+1)*128 + ra] = av0.y;
    aT[(ha+2)*128 + ra] = av0.z;  aT[(ha+3)*128 + ra] = av0.w;
    aT[(ha+4)*128 + ra] = av1.x;  aT[(ha+5)*128 + ra] = av1.y;
    aT[(ha+6)*128 + ra] = av1.z;  aT[(ha+7)*128 + ra] = av1.w;
    *(float4*)&bT[kb*128 + sb]     = bv0;
    *(float4*)&bT[kb*128 + sb + 4] = bv1;
    __syncthreads();
    #pragma unroll
    for (int k = 0; k < 16; ++k) {
      float4 x0 = *(const float4*)&aT[k*128 + ty*8];
      float4 x1 = *(const float4*)&aT[k*128 + ty*8 + 4];
      float4 y0 = *(const float4*)&bT[k*128 + tx*8];
      float4 y1 = *(const float4*)&bT[k*128 + tx*8 + 4];
      float xa[8] = {x0.x,x0.y,x0.z,x0.w,x1.x,x1.y,x1.z,x1.w};
      float yb[8] = {y0.x,y0.y,y0.z,y0.w,y1.x,y1.y,y1.z,y1.w};
      #pragma unroll
      for (int i=0;i<8;++i)
        #pragma unroll
        for (int j2=0;j2<8;++j2) acc[i][j2] += xa[i]*yb[j2];
    }
  }
  // epilogue: relu -> BN affine -> max over this thread's 8 r's -> LDS max -> global max
  float sc[8], sh[8];
  #pragma unroll
  for (int i=0;i<8;++i){
    int r = R0 + ty*8 + i;
    float s = gamma[r] * rsqrtf(var[r] + 1e-5f);
    sc[i] = s;
    sh[i] = beta[r] - mean[r]*s;
  }
  #pragma unroll
  for (int j2=0;j2<8;++j2){
    float m = -3.4e38f;
    #pragma unroll
    for (int i=0;i<8;++i){
      float v = fmaxf(acc[i][j2], 0.0f)*sc[i] + sh[i];
      m = fmaxf(m, v);
    }
    atomicMax(&Lred[tx*8 + j2], encf(m));
  }
  __syncthreads();
  if (tid < 128) atomicMax(&M[b*1024 + P0 + tid], Lred[tid]);
}

// ---------------- K4: decode + clip
__global__ __launch_bounds__(256) void k_final(const unsigned* __restrict__ M, float* __restrict__ out)
{
  int i = blockIdx.x*256 + threadIdx.x; // 16384 exact
  unsigned m = M[i];
  float v = (m & 0x80000000u) ? __uint_as_float(m ^ 0x80000000u) : __uint_as_float(~m);
  out[i] = fminf(fmaxf(v, 0.0f), 1.0f);
}

extern "C" void kernel_launch(void* const* d_in, const int* in_sizes, int n_in,
                              void* d_out, int out_size, void* d_ws, size_t ws_size,
                              hipStream_t stream)
{
  const float* feature = (const float*)d_in[0];
  // d_in[1] = depth (unused), d_in[4] = only_train_rele (unused)
  const int*   idx     = (const int*)d_in[2];
  const int*   lens    = (const int*)d_in[3];
  const float* emb     = (const float*)d_in[5];
  const float* w_ih    = (const float*)d_in[6];
  const float* w_hh    = (const float*)d_in[7];
  const float* b_ih    = (const float*)d_in[8];
  const float* b_hh    = (const float*)d_in[9];
  const float* e2d_w   = (const float*)d_in[10];
  const float* e2d_b   = (const float*)d_in[11];
  const float* lin1_w  = (const float*)d_in[12];
  const float* lin1_b  = (const float*)d_in[13];
  const float* gamma   = (const float*)d_in[14];
  const float* beta    = (const float*)d_in[15];
  const float* mean    = (const float*)d_in[16];
  const float* var     = (const float*)d_in[17];

  char* ws = (char*)d_ws;
  float*    XG     = (float*)(ws);                 // 640*1024*4  = 2621440 B
  float*    instr  = (float*)(ws + 2621440);       // 4096*4      = 16384 B
  float*    f1     = (float*)(ws + 2637824);       // 16*262144*4 = 16777216 B
  unsigned* M      = (unsigned*)(ws + 19415040);   // 16384*4     = 65536 B
  unsigned* whh_bf = (unsigned*)(ws + 19480576);   // 131072*4    = 524288 B  (total ~20 MB)

  hipMemsetAsync(M, 0, 16384*sizeof(unsigned), stream);
  k_xgates   <<<80,  256, 0, stream>>>(idx, emb, w_ih, b_ih, b_hh, XG);
  k_conv_whh <<<512, 256, 0, stream>>>(w_hh, whh_bf);
  k_lstm     <<<16,  256, 0, stream>>>(XG, whh_bf, lens, e2d_w, e2d_b, instr);
  k_lin1     <<<512, 256, 0, stream>>>(instr, lin1_w, lin1_b, f1);
  k_einsum_max<<<256, 256, 0, stream>>>(f1, feature, gamma, beta, mean, var, M);
  k_final    <<<64,  256, 0, stream>>>(M, (float*)d_out);
}

// Round 2
// 787.293 us; speedup vs baseline: 1.6263x; 1.6263x over previous
//
#include <hip/hip_runtime.h>
#include <hip/hip_fp16.h>
#include <math.h>

// Problem constants
#define NB 16     // batch
#define SQ 40     // seq len
#define HIDN 256  // hidden = E = R
#define CC 1024   // C
#define NROW 262144 // R*C

#define AGENT __HIP_MEMORY_SCOPE_AGENT

__device__ __forceinline__ float sigf(float x){ return 1.0f/(1.0f+__expf(-x)); }
// monotone float->uint encoding for atomicMax over floats (any sign)
__device__ __forceinline__ unsigned encf(float x){
  unsigned u = __float_as_uint(x);
  return (u & 0x80000000u) ? ~u : (u | 0x80000000u);
}

typedef _Float16 h2v __attribute__((ext_vector_type(2)));

__device__ __forceinline__ float fd2(unsigned w, unsigned h, float acc){
  h2v a = __builtin_bit_cast(h2v, w);
  h2v b = __builtin_bit_cast(h2v, h);
#if __has_builtin(__builtin_amdgcn_fdot2)
  return __builtin_amdgcn_fdot2(a, b, acc, false);
#else
  return acc + (float)a.x*(float)b.x + (float)a.y*(float)b.y;
#endif
}

__device__ __forceinline__ unsigned pkh(float lo, float hi){
  return (unsigned)__half_as_ushort(__float2half_rn(lo))
       | ((unsigned)__half_as_ushort(__float2half_rn(hi)) << 16);
}

// ---------------- K0: x-gates precompute: XG[t*16+b][row] = emb[idx[b][t]] . w_ih[row] + b_ih + b_hh
__global__ __launch_bounds__(256) void k_xgates(
    const int* __restrict__ idx, const float* __restrict__ emb,
    const float* __restrict__ w_ih, const float* __restrict__ b_ih,
    const float* __restrict__ b_hh, float* __restrict__ XG)
{
  __shared__ float xs[8*256];
  int t = threadIdx.x;
  int tb0 = blockIdx.x * 8;
  #pragma unroll
  for (int i = 0; i < 8; ++i) {
    int flat = t + i*256;
    int p = flat >> 8, k = flat & 255;
    int tb = tb0 + p;
    int ts = tb >> 4, b = tb & 15;
    int row = idx[b*SQ + ts];
    xs[p*256 + k] = emb[row*256 + k];
  }
  __syncthreads();
  int rows[4];
  float acc[4][8];
  #pragma unroll
  for (int r = 0; r < 4; ++r) {
    rows[r] = t + r*256;
    float bias = b_ih[rows[r]] + b_hh[rows[r]];
    #pragma unroll
    for (int p = 0; p < 8; ++p) acc[r][p] = bias;
  }
  for (int k16 = 0; k16 < 16; ++k16) {
    float4 w[4][4];
    #pragma unroll
    for (int r = 0; r < 4; ++r)
      #pragma unroll
      for (int q = 0; q < 4; ++q)
        w[r][q] = *(const float4*)&w_ih[rows[r]*256 + k16*16 + q*4];
    #pragma unroll
    for (int p = 0; p < 8; ++p) {
      #pragma unroll
      for (int q = 0; q < 4; ++q) {
        float4 x = *(const float4*)&xs[p*256 + k16*16 + q*4];
        #pragma unroll
        for (int r = 0; r < 4; ++r)
          acc[r][p] += w[r][q].x*x.x + w[r][q].y*x.y + w[r][q].z*x.z + w[r][q].w*x.w;
      }
    }
  }
  #pragma unroll
  for (int p = 0; p < 8; ++p)
    #pragma unroll
    for (int r = 0; r < 4; ++r)
      XG[(tb0 + p)*1024 + rows[r]] = acc[r][p];
}

// ---------------- K-whh2: reorganize w_hh fp32 -> f16-pair tiles per persistent-LSTM block
// W2 logical layout: [p (8)][oct (32)][r (128)] as uint4 (4 f16-pairs = 8 k-values)
// local row r -> gate g = r>>5, unit u = r&31; global gate-row gr = g*256 + p*32 + u
__global__ __launch_bounds__(256) void k_whh2(const float* __restrict__ w, uint4* __restrict__ W2)
{
  int tid = blockIdx.x*256 + threadIdx.x; // 32768 total
  int p   = tid >> 12;
  int oct = (tid >> 7) & 31;
  int r   = tid & 127;
  int gr  = (r >> 5)*256 + p*32 + (r & 31);
  const float* src = &w[gr*256 + oct*8];
  float4 a = *(const float4*)src;
  float4 b = *(const float4*)(src + 4);
  uint4 o;
  o.x = pkh(a.x, a.y);
  o.y = pkh(a.z, a.w);
  o.z = pkh(b.x, b.y);
  o.w = pkh(b.z, b.w);
  W2[tid] = o;
}

// ---------------- K1: persistent LSTM: 128 blocks = 16 batches x 8 parts; 32 units/block.
// Weights resident in LDS (64KB f16). Per-step cross-block h exchange via agent-scope atomics.
__global__ __launch_bounds__(256) void k_lstm_persist(
    const float* __restrict__ XG, const uint4* __restrict__ W2,
    const int* __restrict__ lens, const float* __restrict__ e2d_w,
    const float* __restrict__ e2d_b, float* __restrict__ instr,
    unsigned* __restrict__ hcomm, unsigned* __restrict__ flags)
{
  __shared__ uint4 wlds[32*128];   // 64 KB: [oct][r]
  __shared__ float dot_s[256];
  __shared__ float h_s[32];
  __shared__ float h_e[256];

  int t = threadIdx.x;
  int b = blockIdx.x >> 3;
  int p = blockIdx.x & 7;
  int len = lens[b];

  // preload weight tile
  const uint4* Wp = W2 + p*4096;
  #pragma unroll
  for (int i = 0; i < 16; ++i) wlds[i*256 + t] = Wp[i*256 + t];
  __syncthreads();

  int r  = t & 127;       // local gate-row
  int kh = t >> 7;        // k-half (0: octs 0..15, 1: octs 16..31)
  int g  = r >> 5, u = r & 31;
  int xg_row = g*256 + p*32 + u;   // global gate-row for XG
  int lane = t & 63;

  unsigned* flag_b = flags + b*16;  // 64B-padded per batch

  float c_reg = 0.0f, h_reg = 0.0f;  // valid for t<32 (unit state)

  for (int it = 0; it < SQ; ++it) {
    // wait for all 8 sibling blocks to have published h_it
    if (it > 0) {
      if (t == 0) {
        while (__hip_atomic_load(flag_b, __ATOMIC_ACQUIRE, AGENT) < (unsigned)(8*it))
          __builtin_amdgcn_s_sleep(2);
      }
      __syncthreads();
    }
    // per-wave full-h: lane l holds packed-f16 pairs 2l, 2l+1 (h[4l..4l+3])
    unsigned hp0 = 0u, hp1 = 0u;
    if (it > 0) {
      const unsigned long long* hc64 =
        (const unsigned long long*)(hcomm + (it & 1)*2048 + b*128);
      unsigned long long v = __hip_atomic_load(&hc64[lane], __ATOMIC_RELAXED, AGENT);
      hp0 = (unsigned)v; hp1 = (unsigned)(v >> 32);
    }
    int hp0i = (int)hp0, hp1i = (int)hp1;

    float a0, a1;
    if (kh == 0) { a0 = XG[(it*NB + b)*1024 + xg_row]; a1 = 0.0f; }
    else         { a0 = 0.0f;                           a1 = 0.0f; }

    int obase = kh*16;
    #pragma unroll
    for (int j = 0; j < 16; ++j) {
      int oct = obase + j;
      uint4 w4 = wlds[oct*128 + r];
      unsigned ha = (unsigned)__builtin_amdgcn_readlane(hp0i, 2*oct);
      unsigned hb = (unsigned)__builtin_amdgcn_readlane(hp1i, 2*oct);
      unsigned hc = (unsigned)__builtin_amdgcn_readlane(hp0i, 2*oct + 1);
      unsigned hd = (unsigned)__builtin_amdgcn_readlane(hp1i, 2*oct + 1);
      a0 = fd2(w4.x, ha, a0);
      a1 = fd2(w4.y, hb, a1);
      a0 = fd2(w4.z, hc, a0);
      a1 = fd2(w4.w, hd, a1);
    }
    dot_s[t] = a0 + a1;
    __syncthreads();

    if (t < 32) {
      float iv = sigf (dot_s[t]       + dot_s[t + 128]);
      float fv = sigf (dot_s[t + 32]  + dot_s[t + 160]);
      float gv = tanhf(dot_s[t + 64]  + dot_s[t + 192]);
      float ov = sigf (dot_s[t + 96]  + dot_s[t + 224]);
      float cn = fv*c_reg + iv*gv;
      float hn = ov*tanhf(cn);
      if (it < len) { c_reg = cn; h_reg = hn; }
      h_s[t] = h_reg;
    }
    __syncthreads();

    if (t < 16) {
      unsigned pk = pkh(h_s[2*t], h_s[2*t + 1]);
      __hip_atomic_store(&hcomm[((it + 1) & 1)*2048 + b*128 + p*16 + t], pk,
                         __ATOMIC_RELAXED, AGENT);
    }
    __syncthreads();
    if (t == 0)
      __hip_atomic_fetch_add(flag_b, 1u, __ATOMIC_RELEASE, AGENT);
  }

  // e2d head, done by p==0 blocks after all parts published h_40 (slot 0)
  if (p == 0) {
    if (t == 0) {
      while (__hip_atomic_load(flag_b, __ATOMIC_ACQUIRE, AGENT) < (unsigned)(8*SQ))
        __builtin_amdgcn_s_sleep(2);
    }
    __syncthreads();
    if (t < 64) {
      const unsigned long long* hc64 = (const unsigned long long*)(hcomm + 0*2048 + b*128);
      unsigned long long v = __hip_atomic_load(&hc64[t], __ATOMIC_RELAXED, AGENT);
      h2v lo = __builtin_bit_cast(h2v, (unsigned)v);
      h2v hi = __builtin_bit_cast(h2v, (unsigned)(v >> 32));
      h_e[4*t + 0] = (float)lo.x;
      h_e[4*t + 1] = (float)lo.y;
      h_e[4*t + 2] = (float)hi.x;
      h_e[4*t + 3] = (float)hi.y;
    }
    __syncthreads();
    float acc = e2d_b[t];
    const float4* wp = (const float4*)&e2d_w[t*256];
    #pragma unroll 8
    for (int k4 = 0; k4 < 64; ++k4) {
      float4 w = wp[k4];
      float4 h4 = *(const float4*)&h_e[k4*4];
      acc += w.x*h4.x + w.y*h4.y + w.z*h4.z + w.w*h4.w;
    }
    instr[b*256 + t] = tanhf(acc);
  }
}

// ---------------- K2: lin1: f1[b][rc] = leaky(instr[b] . lin1_w[rc] + lin1_b[rc]); 2 rows/thread, 512 blocks
__global__ __launch_bounds__(256) void k_lin1(
    const float* __restrict__ instr, const float* __restrict__ w,
    const float* __restrict__ bias, float* __restrict__ f1)
{
  __shared__ float is[4096];
  int t = threadIdx.x;
  #pragma unroll
  for (int i = 0; i < 16; ++i) is[t + i*256] = instr[t + i*256];
  __syncthreads();
  int r0 = blockIdx.x*512 + t;
  int r1 = r0 + 256;
  const float* w0 = &w[(size_t)r0*256];
  const float* w1 = &w[(size_t)r1*256];
  float acc0[16], acc1[16];
  float bz0 = bias[r0], bz1 = bias[r1];
  #pragma unroll
  for (int i = 0; i < 16; ++i){ acc0[i]=bz0; acc1[i]=bz1; }
  for (int k16 = 0; k16 < 16; ++k16) {
    float4 a[4], bb[4];
    #pragma unroll
    for (int q = 0; q < 4; ++q){
      a[q]  = *(const float4*)&w0[k16*16 + q*4];
      bb[q] = *(const float4*)&w1[k16*16 + q*4];
    }
    #pragma unroll
    for (int bi = 0; bi < 16; ++bi) {
      #pragma unroll
      for (int q = 0; q < 4; ++q) {
        float4 x = *(const float4*)&is[bi*256 + k16*16 + q*4]; // uniform addr -> LDS broadcast
        acc0[bi] += a[q].x*x.x + a[q].y*x.y + a[q].z*x.z + a[q].w*x.w;
        acc1[bi] += bb[q].x*x.x + bb[q].y*x.y + bb[q].z*x.z + bb[q].w*x.w;
      }
    }
  }
  #pragma unroll
  for (int bi = 0; bi < 16; ++bi) {
    float v0 = acc0[bi]; v0 = v0 > 0.0f ? v0 : 0.01f*v0;
    float v1 = acc1[bi]; v1 = v1 > 0.0f ? v1 : 0.01f*v1;
    f1[bi*NROW + r0] = v0;
    f1[bi*NROW + r1] = v1;
  }
}

// ---------------- K3: per-batch gemm f1[b](256x1024) @ feat[b](1024x1024), fused relu->BN->max_r via atomicMax
__global__ __launch_bounds__(256) void k_einsum_max(
    const float* __restrict__ f1, const float* __restrict__ feat,
    const float* __restrict__ gamma, const float* __restrict__ beta,
    const float* __restrict__ mean, const float* __restrict__ var,
    unsigned* __restrict__ M)
{
  __shared__ float aT[16*128];      // [k][r]
  __shared__ float bT[16*128];      // [k][p]
  __shared__ unsigned Lred[128];
  int tid = threadIdx.x;
  int b   = blockIdx.x >> 4;
  int rem = blockIdx.x & 15;
  int R0  = (rem >> 3) * 128;
  int P0  = (rem & 7) * 128;
  int tx = tid & 15, ty = tid >> 4;
  if (tid < 128) Lred[tid] = 0u;
  float acc[8][8];
  #pragma unroll
  for (int i=0;i<8;++i)
    #pragma unroll
    for (int j2=0;j2<8;++j2) acc[i][j2]=0.0f;
  int ra = tid >> 1, ha = (tid & 1) * 8;   // A staging: row, k-offset
  int kb = tid >> 4, sb = (tid & 15) * 8;  // B staging: k, p-offset
  const float* Abase = &f1[(b*256 + R0 + ra)*1024 + ha];
  const float* Bbase = &feat[((b*1024) + kb)*1024 + P0 + sb];
  for (int kk = 0; kk < 64; ++kk) {
    int k0 = kk*16;
    __syncthreads();
    float4 av0 = *(const float4*)&Abase[k0];
    float4 av1 = *(const float4*)&Abase[k0+4];
    float4 bv0 = *(const float4*)&Bbase[(size_t)k0*1024];
    float4 bv1 = *(const float4*)&Bbase[(size_t)k0*1024 + 4];
    aT[(ha+0)*128 + ra] = av0.x;  aT[(ha+1)*128 + ra] = av0.y;
    aT[(ha+2)*128 + ra] = av0.z;  aT[(ha+3)*128 + ra] = av0.w;
    aT[(ha+4)*128 + ra] = av1.x;  aT[(ha+5)*128 + ra] = av1.y;
    aT[(ha+6)*128 + ra] = av1.z;  aT[(ha+7)*128 + ra] = av1.w;
    *(float4*)&bT[kb*128 + sb]     = bv0;
    *(float4*)&bT[kb*128 + sb + 4] = bv1;
    __syncthreads();
    #pragma unroll
    for (int k = 0; k < 16; ++k) {
      float4 x0 = *(const float4*)&aT[k*128 + ty*8];
      float4 x1 = *(const float4*)&aT[k*128 + ty*8 + 4];
      float4 y0 = *(const float4*)&bT[k*128 + tx*8];
      float4 y1 = *(const float4*)&bT[k*128 + tx*8 + 4];
      float xa[8] = {x0.x,x0.y,x0.z,x0.w,x1.x,x1.y,x1.z,x1.w};
      float yb[8] = {y0.x,y0.y,y0.z,y0.w,y1.x,y1.y,y1.z,y1.w};
      #pragma unroll
      for (int i=0;i<8;++i)
        #pragma unroll
        for (int j2=0;j2<8;++j2) acc[i][j2] += xa[i]*yb[j2];
    }
  }
  float sc[8], sh[8];
  #pragma unroll
  for (int i=0;i<8;++i){
    int rr = R0 + ty*8 + i;
    float s = gamma[rr] * rsqrtf(var[rr] + 1e-5f);
    sc[i] = s;
    sh[i] = beta[rr] - mean[rr]*s;
  }
  #pragma unroll
  for (int j2=0;j2<8;++j2){
    float m = -3.4e38f;
    #pragma unroll
    for (int i=0;i<8;++i){
      float v = fmaxf(acc[i][j2], 0.0f)*sc[i] + sh[i];
      m = fmaxf(m, v);
    }
    atomicMax(&Lred[tx*8 + j2], encf(m));
  }
  __syncthreads();
  if (tid < 128) atomicMax(&M[b*1024 + P0 + tid], Lred[tid]);
}

// ---------------- K4: decode + clip
__global__ __launch_bounds__(256) void k_final(const unsigned* __restrict__ M, float* __restrict__ out)
{
  int i = blockIdx.x*256 + threadIdx.x; // 16384 exact
  unsigned m = M[i];
  float v = (m & 0x80000000u) ? __uint_as_float(m ^ 0x80000000u) : __uint_as_float(~m);
  out[i] = fminf(fmaxf(v, 0.0f), 1.0f);
}

extern "C" void kernel_launch(void* const* d_in, const int* in_sizes, int n_in,
                              void* d_out, int out_size, void* d_ws, size_t ws_size,
                              hipStream_t stream)
{
  const float* feature = (const float*)d_in[0];
  // d_in[1] = depth (unused), d_in[4] = only_train_rele (unused)
  const int*   idx     = (const int*)d_in[2];
  const int*   lens    = (const int*)d_in[3];
  const float* emb     = (const float*)d_in[5];
  const float* w_ih    = (const float*)d_in[6];
  const float* w_hh    = (const float*)d_in[7];
  const float* b_ih    = (const float*)d_in[8];
  const float* b_hh    = (const float*)d_in[9];
  const float* e2d_w   = (const float*)d_in[10];
  const float* e2d_b   = (const float*)d_in[11];
  const float* lin1_w  = (const float*)d_in[12];
  const float* lin1_b  = (const float*)d_in[13];
  const float* gamma   = (const float*)d_in[14];
  const float* beta    = (const float*)d_in[15];
  const float* mean    = (const float*)d_in[16];
  const float* var     = (const float*)d_in[17];

  char* ws = (char*)d_ws;
  float*    XG     = (float*)(ws);                 // 640*1024*4  = 2,621,440 B
  float*    instr  = (float*)(ws + 2621440);       // 4096*4      = 16,384 B
  float*    f1     = (float*)(ws + 2637824);       // 16*262144*4 = 16,777,216 B
  unsigned* M      = (unsigned*)(ws + 19415040);   // 16384*4     = 65,536 B
  // LSTM-phase scratch aliases the f1 region (f1 is written only AFTER the LSTM kernel):
  uint4*    W2     = (uint4*)(ws + 2637824);               // 512 KB
  unsigned* hcomm  = (unsigned*)(ws + 2637824 + 524288);   // 2*16*128*4 = 16 KB
  unsigned* flags  = (unsigned*)(ws + 2637824 + 540672);   // 16*16*4 = 1 KB

  hipMemsetAsync(M, 0, 16384*sizeof(unsigned), stream);
  hipMemsetAsync(flags, 0, 1024, stream);
  k_xgates      <<<80,  256, 0, stream>>>(idx, emb, w_ih, b_ih, b_hh, XG);
  k_whh2        <<<128, 256, 0, stream>>>(w_hh, W2);
  k_lstm_persist<<<128, 256, 0, stream>>>(XG, W2, lens, e2d_w, e2d_b, instr, hcomm, flags);
  k_lin1        <<<512, 256, 0, stream>>>(instr, lin1_w, lin1_b, f1);
  k_einsum_max  <<<256, 256, 0, stream>>>(f1, feature, gamma, beta, mean, var, M);
  k_final       <<<64,  256, 0, stream>>>(M, (float*)d_out);
}

// Round 3
// 693.774 us; speedup vs baseline: 1.8455x; 1.1348x over previous
//
#include <hip/hip_runtime.h>
#include <hip/hip_fp16.h>
#include <math.h>

// Problem constants
#define NB 16     // batch
#define SQ 40     // seq len
#define HIDN 256  // hidden = E = R
#define CC 1024   // C
#define NROW 262144 // R*C

#define AGENT __HIP_MEMORY_SCOPE_AGENT

__device__ __forceinline__ float sigf(float x){ return 1.0f/(1.0f+__expf(-x)); }

typedef _Float16 h2v __attribute__((ext_vector_type(2)));
typedef _Float16 f16x8 __attribute__((ext_vector_type(8)));
typedef float    f32x4 __attribute__((ext_vector_type(4)));

__device__ __forceinline__ float fd2(unsigned w, unsigned h, float acc){
  h2v a = __builtin_bit_cast(h2v, w);
  h2v b = __builtin_bit_cast(h2v, h);
#if __has_builtin(__builtin_amdgcn_fdot2)
  return __builtin_amdgcn_fdot2(a, b, acc, false);
#else
  return acc + (float)a.x*(float)b.x + (float)a.y*(float)b.y;
#endif
}

__device__ __forceinline__ unsigned pkh(float lo, float hi){
  return (unsigned)__half_as_ushort(__float2half_rn(lo))
       | ((unsigned)__half_as_ushort(__float2half_rn(hi)) << 16);
}

// ---------------- K0: x-gates precompute: XG[t*16+b][row] = emb[idx[b][t]] . w_ih[row] + b_ih + b_hh
__global__ __launch_bounds__(256) void k_xgates(
    const int* __restrict__ idx, const float* __restrict__ emb,
    const float* __restrict__ w_ih, const float* __restrict__ b_ih,
    const float* __restrict__ b_hh, float* __restrict__ XG)
{
  __shared__ float xs[8*256];
  int t = threadIdx.x;
  int tb0 = blockIdx.x * 8;
  #pragma unroll
  for (int i = 0; i < 8; ++i) {
    int flat = t + i*256;
    int p = flat >> 8, k = flat & 255;
    int tb = tb0 + p;
    int ts = tb >> 4, b = tb & 15;
    int row = idx[b*SQ + ts];
    xs[p*256 + k] = emb[row*256 + k];
  }
  __syncthreads();
  int rows[4];
  float acc[4][8];
  #pragma unroll
  for (int r = 0; r < 4; ++r) {
    rows[r] = t + r*256;
    float bias = b_ih[rows[r]] + b_hh[rows[r]];
    #pragma unroll
    for (int p = 0; p < 8; ++p) acc[r][p] = bias;
  }
  for (int k16 = 0; k16 < 16; ++k16) {
    float4 w[4][4];
    #pragma unroll
    for (int r = 0; r < 4; ++r)
      #pragma unroll
      for (int q = 0; q < 4; ++q)
        w[r][q] = *(const float4*)&w_ih[rows[r]*256 + k16*16 + q*4];
    #pragma unroll
    for (int p = 0; p < 8; ++p) {
      #pragma unroll
      for (int q = 0; q < 4; ++q) {
        float4 x = *(const float4*)&xs[p*256 + k16*16 + q*4];
        #pragma unroll
        for (int r = 0; r < 4; ++r)
          acc[r][p] += w[r][q].x*x.x + w[r][q].y*x.y + w[r][q].z*x.z + w[r][q].w*x.w;
      }
    }
  }
  #pragma unroll
  for (int p = 0; p < 8; ++p)
    #pragma unroll
    for (int r = 0; r < 4; ++r)
      XG[(tb0 + p)*1024 + rows[r]] = acc[r][p];
}

// ---------------- K-whh2: reorganize w_hh fp32 -> f16-pair tiles per persistent-LSTM block
__global__ __launch_bounds__(256) void k_whh2(const float* __restrict__ w, uint4* __restrict__ W2)
{
  int tid = blockIdx.x*256 + threadIdx.x; // 32768 total
  int p   = tid >> 12;
  int oct = (tid >> 7) & 31;
  int r   = tid & 127;
  int gr  = (r >> 5)*256 + p*32 + (r & 31);
  const float* src = &w[gr*256 + oct*8];
  float4 a = *(const float4*)src;
  float4 b = *(const float4*)(src + 4);
  uint4 o;
  o.x = pkh(a.x, a.y);
  o.y = pkh(a.z, a.w);
  o.z = pkh(b.x, b.y);
  o.w = pkh(b.z, b.w);
  W2[tid] = o;
}

// ---------------- K1: persistent LSTM: 128 blocks = 16 batches x 8 parts; 32 units/block.
__global__ __launch_bounds__(256) void k_lstm_persist(
    const float* __restrict__ XG, const uint4* __restrict__ W2,
    const int* __restrict__ lens, const float* __restrict__ e2d_w,
    const float* __restrict__ e2d_b, float* __restrict__ instr,
    unsigned* __restrict__ hcomm, unsigned* __restrict__ flags)
{
  __shared__ uint4 wlds[32*128];   // 64 KB: [oct][r]
  __shared__ float dot_s[256];
  __shared__ float h_s[32];
  __shared__ float h_e[256];

  int t = threadIdx.x;
  int b = blockIdx.x >> 3;
  int p = blockIdx.x & 7;
  int len = lens[b];

  const uint4* Wp = W2 + p*4096;
  #pragma unroll
  for (int i = 0; i < 16; ++i) wlds[i*256 + t] = Wp[i*256 + t];
  __syncthreads();

  int r  = t & 127;
  int kh = t >> 7;
  int g  = r >> 5, u = r & 31;
  int xg_row = g*256 + p*32 + u;
  int lane = t & 63;

  unsigned* flag_b = flags + b*16;

  float c_reg = 0.0f, h_reg = 0.0f;

  for (int it = 0; it < SQ; ++it) {
    if (it > 0) {
      if (t == 0) {
        while (__hip_atomic_load(flag_b, __ATOMIC_ACQUIRE, AGENT) < (unsigned)(8*it))
          __builtin_amdgcn_s_sleep(2);
      }
      __syncthreads();
    }
    unsigned hp0 = 0u, hp1 = 0u;
    if (it > 0) {
      const unsigned long long* hc64 =
        (const unsigned long long*)(hcomm + (it & 1)*2048 + b*128);
      unsigned long long v = __hip_atomic_load(&hc64[lane], __ATOMIC_RELAXED, AGENT);
      hp0 = (unsigned)v; hp1 = (unsigned)(v >> 32);
    }
    int hp0i = (int)hp0, hp1i = (int)hp1;

    float a0, a1;
    if (kh == 0) { a0 = XG[(it*NB + b)*1024 + xg_row]; a1 = 0.0f; }
    else         { a0 = 0.0f;                           a1 = 0.0f; }

    int obase = kh*16;
    #pragma unroll
    for (int j = 0; j < 16; ++j) {
      int oct = obase + j;
      uint4 w4 = wlds[oct*128 + r];
      unsigned ha = (unsigned)__builtin_amdgcn_readlane(hp0i, 2*oct);
      unsigned hb = (unsigned)__builtin_amdgcn_readlane(hp1i, 2*oct);
      unsigned hc = (unsigned)__builtin_amdgcn_readlane(hp0i, 2*oct + 1);
      unsigned hd = (unsigned)__builtin_amdgcn_readlane(hp1i, 2*oct + 1);
      a0 = fd2(w4.x, ha, a0);
      a1 = fd2(w4.y, hb, a1);
      a0 = fd2(w4.z, hc, a0);
      a1 = fd2(w4.w, hd, a1);
    }
    dot_s[t] = a0 + a1;
    __syncthreads();

    if (t < 32) {
      float iv = sigf (dot_s[t]       + dot_s[t + 128]);
      float fv = sigf (dot_s[t + 32]  + dot_s[t + 160]);
      float gv = tanhf(dot_s[t + 64]  + dot_s[t + 192]);
      float ov = sigf (dot_s[t + 96]  + dot_s[t + 224]);
      float cn = fv*c_reg + iv*gv;
      float hn = ov*tanhf(cn);
      if (it < len) { c_reg = cn; h_reg = hn; }
      h_s[t] = h_reg;
    }
    __syncthreads();

    if (t < 16) {
      unsigned pk = pkh(h_s[2*t], h_s[2*t + 1]);
      __hip_atomic_store(&hcomm[((it + 1) & 1)*2048 + b*128 + p*16 + t], pk,
                         __ATOMIC_RELAXED, AGENT);
    }
    __syncthreads();
    if (t == 0)
      __hip_atomic_fetch_add(flag_b, 1u, __ATOMIC_RELEASE, AGENT);
  }

  if (p == 0) {
    if (t == 0) {
      while (__hip_atomic_load(flag_b, __ATOMIC_ACQUIRE, AGENT) < (unsigned)(8*SQ))
        __builtin_amdgcn_s_sleep(2);
    }
    __syncthreads();
    if (t < 64) {
      const unsigned long long* hc64 = (const unsigned long long*)(hcomm + 0*2048 + b*128);
      unsigned long long v = __hip_atomic_load(&hc64[t], __ATOMIC_RELAXED, AGENT);
      h2v lo = __builtin_bit_cast(h2v, (unsigned)v);
      h2v hi = __builtin_bit_cast(h2v, (unsigned)(v >> 32));
      h_e[4*t + 0] = (float)lo.x;
      h_e[4*t + 1] = (float)lo.y;
      h_e[4*t + 2] = (float)hi.x;
      h_e[4*t + 3] = (float)hi.y;
    }
    __syncthreads();
    float acc = e2d_b[t];
    const float4* wp = (const float4*)&e2d_w[t*256];
    #pragma unroll 8
    for (int k4 = 0; k4 < 64; ++k4) {
      float4 w = wp[k4];
      float4 h4 = *(const float4*)&h_e[k4*4];
      acc += w.x*h4.x + w.y*h4.y + w.z*h4.z + w.w*h4.w;
    }
    instr[b*256 + t] = tanhf(acc);
  }
}

// ---------------- K2: lin1 -> f16 output: f1h[b][rc] = (half)leaky(instr[b].lin1_w[rc] + lin1_b[rc])
__global__ __launch_bounds__(256) void k_lin1(
    const float* __restrict__ instr, const float* __restrict__ w,
    const float* __restrict__ bias, _Float16* __restrict__ f1h)
{
  __shared__ float is[4096];
  int t = threadIdx.x;
  #pragma unroll
  for (int i = 0; i < 16; ++i) is[t + i*256] = instr[t + i*256];
  __syncthreads();
  int r0 = blockIdx.x*512 + t;
  int r1 = r0 + 256;
  const float* w0 = &w[(size_t)r0*256];
  const float* w1 = &w[(size_t)r1*256];
  float acc0[16], acc1[16];
  float bz0 = bias[r0], bz1 = bias[r1];
  #pragma unroll
  for (int i = 0; i < 16; ++i){ acc0[i]=bz0; acc1[i]=bz1; }
  for (int k16 = 0; k16 < 16; ++k16) {
    float4 a[4], bb[4];
    #pragma unroll
    for (int q = 0; q < 4; ++q){
      a[q]  = *(const float4*)&w0[k16*16 + q*4];
      bb[q] = *(const float4*)&w1[k16*16 + q*4];
    }
    #pragma unroll
    for (int bi = 0; bi < 16; ++bi) {
      #pragma unroll
      for (int q = 0; q < 4; ++q) {
        float4 x = *(const float4*)&is[bi*256 + k16*16 + q*4];
        acc0[bi] += a[q].x*x.x + a[q].y*x.y + a[q].z*x.z + a[q].w*x.w;
        acc1[bi] += bb[q].x*x.x + bb[q].y*x.y + bb[q].z*x.z + bb[q].w*x.w;
      }
    }
  }
  #pragma unroll
  for (int bi = 0; bi < 16; ++bi) {
    float v0 = acc0[bi]; v0 = v0 > 0.0f ? v0 : 0.01f*v0;
    float v1 = acc1[bi]; v1 = v1 > 0.0f ? v1 : 0.01f*v1;
    f1h[(size_t)bi*NROW + r0] = (_Float16)v0;
    f1h[(size_t)bi*NROW + r1] = (_Float16)v1;
  }
}

// ---------------- K3: f16 MFMA einsum + fused relu->BN->max_r->clip, writes d_out directly.
// Grid: 128 blocks = 16 b x 8 p-tiles(128). Block tile: 256 r x 128 p, K=1024 in chunks of 32.
// A = f1h[b] (256r x 1024k, k-contig), staged [r][k] rows (80B stride).
// B = feat[b] (1024k x 1024p), transposed in-LDS to [p][k] rows (80B stride).
// mfma_f32_16x16x32_f16: D[m=r][n=p]; C/D: col(n)=lane&15, row(m)=(lane>>4)*4+reg.
__global__ __launch_bounds__(256, 1) void k_einsum_mfma(
    const uint4* __restrict__ f1h4, const float* __restrict__ feat,
    const float* __restrict__ gamma, const float* __restrict__ beta,
    const float* __restrict__ mean, const float* __restrict__ var,
    float* __restrict__ out)
{
  __shared__ unsigned ALDS[256*20];  // [r][40 halves] (32 k + 8 pad) = 20 KB
  __shared__ unsigned BLDS[128*20];  // [p][40 halves]                = 10 KB
  __shared__ float sc_s[256], sh_s[256];
  __shared__ float red[2][128];

  int t = threadIdx.x;
  int b  = blockIdx.x >> 3;
  int P0 = (blockIdx.x & 7) * 128;
  int wid  = t >> 6, lane = t & 63;
  int wp = wid & 1, wr = wid >> 1;   // wave tile: 128 r (wr) x 64 p (wp)
  int col = lane & 15, quad = lane >> 4;

  // BN constants
  {
    float s = gamma[t] * rsqrtf(var[t] + 1e-5f);
    sc_s[t] = s;
    sh_s[t] = beta[t] - mean[t]*s;
  }

  f32x4 acc[8][4];
  #pragma unroll
  for (int mt = 0; mt < 8; ++mt)
    #pragma unroll
    for (int nt = 0; nt < 4; ++nt) acc[mt][nt] = (f32x4)0.0f;

  // staging thread roles
  const uint4* arow = f1h4 + ((size_t)b*NROW + (size_t)t*1024)/8;  // f1h row t, uint4 units
  int p_loc = t & 127, khalf = t >> 7;
  const float* bbase = feat + ((size_t)b*1024 + khalf*16)*1024 + P0 + p_loc;

  // prefetch chunk 0
  uint4 apf[4];
  float bpf[16];
  #pragma unroll
  for (int g = 0; g < 4; ++g) apf[g] = arow[g];
  #pragma unroll
  for (int j = 0; j < 16; ++j) bpf[j] = bbase[(size_t)j*1024];

  for (int kc = 0; kc < 32; ++kc) {
    __syncthreads();   // previous frag reads done; sc_s visible on first iter
    // write staged chunk
    #pragma unroll
    for (int g = 0; g < 4; ++g)
      *(uint4*)&ALDS[t*20 + g*4] = apf[g];
    {
      unsigned u[8];
      #pragma unroll
      for (int i = 0; i < 8; ++i) u[i] = pkh(bpf[2*i], bpf[2*i+1]);
      uint4 w0 = {u[0],u[1],u[2],u[3]}, w1 = {u[4],u[5],u[6],u[7]};
      *(uint4*)&BLDS[p_loc*20 + khalf*8]     = w0;
      *(uint4*)&BLDS[p_loc*20 + khalf*8 + 4] = w1;
    }
    __syncthreads();
    // prefetch next chunk (overlaps MFMA below)
    if (kc + 1 < 32) {
      #pragma unroll
      for (int g = 0; g < 4; ++g) apf[g] = arow[(kc+1)*4 + g];
      const float* bb = bbase + (size_t)(kc+1)*32*1024;
      #pragma unroll
      for (int j = 0; j < 16; ++j) bpf[j] = bb[(size_t)j*1024];
    }
    // fragments + MFMA
    f16x8 bf[4];
    #pragma unroll
    for (int nt = 0; nt < 4; ++nt) {
      uint4 raw = *(const uint4*)&BLDS[(wp*64 + nt*16 + col)*20 + quad*4];
      bf[nt] = __builtin_bit_cast(f16x8, raw);
    }
    #pragma unroll
    for (int mt = 0; mt < 8; ++mt) {
      uint4 raw = *(const uint4*)&ALDS[(wr*128 + mt*16 + col)*20 + quad*4];
      f16x8 af = __builtin_bit_cast(f16x8, raw);
      #pragma unroll
      for (int nt = 0; nt < 4; ++nt)
        acc[mt][nt] = __builtin_amdgcn_mfma_f32_16x16x32_f16(af, bf[nt], acc[mt][nt], 0, 0, 0);
    }
  }

  // epilogue: relu -> BN -> max over r -> clip -> store
  float pmax[4];
  #pragma unroll
  for (int nt = 0; nt < 4; ++nt) pmax[nt] = -3.4e38f;
  #pragma unroll
  for (int mt = 0; mt < 8; ++mt) {
    int rb = wr*128 + mt*16 + quad*4;
    f32x4 scv = *(const f32x4*)&sc_s[rb];
    f32x4 shv = *(const f32x4*)&sh_s[rb];
    #pragma unroll
    for (int nt = 0; nt < 4; ++nt) {
      f32x4 a = acc[mt][nt];
      #pragma unroll
      for (int reg = 0; reg < 4; ++reg) {
        float v = fmaxf(a[reg], 0.0f)*scv[reg] + shv[reg];
        pmax[nt] = fmaxf(pmax[nt], v);
      }
    }
  }
  #pragma unroll
  for (int nt = 0; nt < 4; ++nt) {
    float m = pmax[nt];
    m = fmaxf(m, __shfl_xor(m, 16));
    m = fmaxf(m, __shfl_xor(m, 32));
    if (lane < 16) red[wr][wp*64 + nt*16 + lane] = m;
  }
  __syncthreads();
  if (t < 128) {
    float v = fmaxf(red[0][t], red[1][t]);
    out[b*1024 + P0 + t] = fminf(fmaxf(v, 0.0f), 1.0f);
  }
}

extern "C" void kernel_launch(void* const* d_in, const int* in_sizes, int n_in,
                              void* d_out, int out_size, void* d_ws, size_t ws_size,
                              hipStream_t stream)
{
  const float* feature = (const float*)d_in[0];
  // d_in[1] = depth (unused), d_in[4] = only_train_rele (unused)
  const int*   idx     = (const int*)d_in[2];
  const int*   lens    = (const int*)d_in[3];
  const float* emb     = (const float*)d_in[5];
  const float* w_ih    = (const float*)d_in[6];
  const float* w_hh    = (const float*)d_in[7];
  const float* b_ih    = (const float*)d_in[8];
  const float* b_hh    = (const float*)d_in[9];
  const float* e2d_w   = (const float*)d_in[10];
  const float* e2d_b   = (const float*)d_in[11];
  const float* lin1_w  = (const float*)d_in[12];
  const float* lin1_b  = (const float*)d_in[13];
  const float* gamma   = (const float*)d_in[14];
  const float* beta    = (const float*)d_in[15];
  const float* mean    = (const float*)d_in[16];
  const float* var     = (const float*)d_in[17];

  char* ws = (char*)d_ws;
  float*    XG     = (float*)(ws);                 // 640*1024*4  = 2,621,440 B
  float*    instr  = (float*)(ws + 2621440);       // 4096*4      = 16,384 B
  uint4*    W2     = (uint4*)(ws + 2637824);       // 512 KB
  unsigned* hcomm  = (unsigned*)(ws + 3162112);    // 16 KB
  unsigned* flags  = (unsigned*)(ws + 3178496);    // 1 KB
  _Float16* f1h    = (_Float16*)(ws + 3179520);    // 16*262144*2 = 8,388,608 B  (total ~11.6 MB)

  hipMemsetAsync(flags, 0, 1024, stream);
  k_xgates      <<<80,  256, 0, stream>>>(idx, emb, w_ih, b_ih, b_hh, XG);
  k_whh2        <<<128, 256, 0, stream>>>(w_hh, W2);
  k_lstm_persist<<<128, 256, 0, stream>>>(XG, W2, lens, e2d_w, e2d_b, instr, hcomm, flags);
  k_lin1        <<<512, 256, 0, stream>>>(instr, lin1_w, lin1_b, f1h);
  k_einsum_mfma <<<128, 256, 0, stream>>>((const uint4*)f1h, feature, gamma, beta, mean, var,
                                          (float*)d_out);
}